// Round 1
// baseline (30.060 us; speedup 1.0000x reference)
//
#include <hip/hip_runtime.h>

#define B_TOT 1024
#define SEQ 64
#define IND 32
#define HID 8

// DPP helper (VALU-rate cross-lane within 16-lane rows)
template<int CTRL>
__device__ __forceinline__ float dppf(float v) {
    return __int_as_float(__builtin_amdgcn_update_dpp(
        0, __float_as_int(v), CTRL, 0xF, 0xF, true));
}
// ds_swizzle helper (within each 32-lane half of the wave)
template<int OFF>
__device__ __forceinline__ float swzf(float v) {
    return __int_as_float(__builtin_amdgcn_ds_swizzle(__float_as_int(v), OFF));
}

__global__ __launch_bounds__(64, 1) void qlstm_kernel(
    const float* __restrict__ xin,
    const float* __restrict__ Wf, const float* __restrict__ bf, const float* __restrict__ thf,
    const float* __restrict__ Wi, const float* __restrict__ bi, const float* __restrict__ thi,
    const float* __restrict__ Wu, const float* __restrict__ bu, const float* __restrict__ thu,
    const float* __restrict__ Wo, const float* __restrict__ bo, const float* __restrict__ tho,
    float* __restrict__ out)
{
    const int lane = threadIdx.x & 63;
    const int l32  = lane & 31;
    const int gate = l32 >> 3;   // 0=f 1=i 2=g(update) 3=o
    const int row  = l32 & 7;    // wire / hidden index
    const int b    = blockIdx.x * 2 + (lane >> 5);

    const float* Wg = (gate == 0) ? Wf : (gate == 1) ? Wi : (gate == 2) ? Wu : Wo;
    const float* bg = (gate == 0) ? bf : (gate == 1) ? bi : (gate == 2) ? bu : bo;
    const float* tg = (gate == 0) ? thf : (gate == 1) ? thi : (gate == 2) ? thu : tho;

    // per-lane weight row: 32 x-weights (vec4) + 8 h-weights
    float4 wx[8];
    const float4* wp = (const float4*)(Wg + row * 40);
    #pragma unroll
    for (int k = 0; k < 8; ++k) wx[k] = wp[k];
    float wh[8];
    #pragma unroll
    for (int k = 0; k < 8; ++k) wh[k] = Wg[row * 40 + 32 + k];
    const float bt = bg[row] + tg[row];   // cos argument offset: y + b + theta

    // unified activation constants: sigmoid for f/i/o, tanh for g
    const float es = (gate == 2) ? 2.0f : -1.0f;
    const float aA = (gate == 2) ? 1.0f : 0.0f;
    const float aB = (gate == 2) ? -2.0f : 1.0f;

    const float* xbase = xin + (size_t)b * (SEQ * IND);
    float* oseq = out + (size_t)b * (SEQ * HID);

    float hxv[8] = {0,0,0,0,0,0,0,0};   // broadcast copy of hx on every lane
    float cx = 0.0f, hlast = 0.0f;

    float4 xa[8], xb[8];
    {
        const float4* p = (const float4*)xbase;
        #pragma unroll
        for (int k = 0; k < 8; ++k) xa[k] = p[k];
    }

    auto loadx = [&](float4 (&xv)[8], int t) {
        const float4* p = (const float4*)(xbase + t * IND);
        #pragma unroll
        for (int k = 0; k < 8; ++k) xv[k] = p[k];
    };

    auto step = [&](const float4 (&xv)[8], int t) {
        // 40-length dot product, 4 accumulators for ILP
        float d0 = bt, d1 = 0.f, d2 = 0.f, d3 = 0.f;
        #pragma unroll
        for (int k = 0; k < 8; ++k) {
            d0 = fmaf(wx[k].x, xv[k].x, d0);
            d1 = fmaf(wx[k].y, xv[k].y, d1);
            d2 = fmaf(wx[k].z, xv[k].z, d2);
            d3 = fmaf(wx[k].w, xv[k].w, d3);
        }
        d0 = fmaf(wh[0], hxv[0], d0); d1 = fmaf(wh[1], hxv[1], d1);
        d2 = fmaf(wh[2], hxv[2], d2); d3 = fmaf(wh[3], hxv[3], d3);
        d0 = fmaf(wh[4], hxv[4], d0); d1 = fmaf(wh[5], hxv[5], d1);
        d2 = fmaf(wh[6], hxv[6], d2); d3 = fmaf(wh[7], hxv[7], d3);
        float y = (d0 + d1) + (d2 + d3);

        // c = cos(y) via v_cos (revolutions + fract reduction)
        float r = y * 0.15915494309189535f;
        r = __builtin_amdgcn_fractf(r);
        float c = __builtin_amdgcn_cosf(r);

        // prefix products over the 8-lane row group (DPP, all-VALU):
        //  v[row] = c0..c_row   (output for wires 1..7)
        //  w-scan seeded 1 at row0 -> w[7] = c1..c7; half-mirror gives it to row0
        float v = c;
        float w = (row == 0) ? 1.0f : c;
        float tv, tw;
        tv = dppf<0x111>(v); tw = dppf<0x111>(w);      // row_shr:1
        if (row >= 1) { v *= tv; w *= tw; }
        tv = dppf<0x112>(v); tw = dppf<0x112>(w);      // row_shr:2
        if (row >= 2) { v *= tv; w *= tw; }
        tv = dppf<0x114>(v); tw = dppf<0x114>(w);      // row_shr:4
        if (row >= 4) { v *= tv; w *= tw; }
        float full = dppf<0x141>(w);                   // row_half_mirror: row0 <- row7
        float q = (row == 0) ? full : v;

        // activation (no divergence): r = 1/(1+exp(q*es)); act = aB*r + aA
        float e  = __expf(q * es);
        float rr = __builtin_amdgcn_rcpf(1.0f + e);
        float act = fmaf(aB, rr, aA);

        // bring i, g, o to the gate-0 lanes (XOR swizzles within 32 lanes)
        float iv = swzf<0x201f>(act);   // lane ^ 8
        float gv = swzf<0x401f>(act);   // lane ^ 16
        float ov = swzf<0x601f>(act);   // lane ^ 24

        // LSTM update (valid on lanes 0..7; harmless bounded garbage elsewhere)
        cx = fmaf(act, cx, iv * gv);
        float e2 = __expf(2.0f * cx);
        float th = 1.0f - 2.0f * __builtin_amdgcn_rcpf(1.0f + e2);
        float h2 = ov * th;
        hlast = h2;

        if (l32 < 8) oseq[t * HID + row] = h2;

        // broadcast new hx[0..7] from lanes 0..7 to every lane of the group
        hxv[0] = swzf<0x000>(h2);
        hxv[1] = swzf<0x020>(h2);
        hxv[2] = swzf<0x040>(h2);
        hxv[3] = swzf<0x060>(h2);
        hxv[4] = swzf<0x080>(h2);
        hxv[5] = swzf<0x0A0>(h2);
        hxv[6] = swzf<0x0C0>(h2);
        hxv[7] = swzf<0x0E0>(h2);
    };

    // 2-step software pipeline: x(t+1) loads issue before step(t)'s serial chain
    #pragma unroll 1
    for (int t = 0; t < SEQ; t += 2) {
        loadx(xb, t + 1);
        step(xa, t);
        loadx(xa, (t + 2) & 63);   // wraps to 0 at the end (harmless, in-bounds)
        step(xb, t + 1);
    }

    if (l32 < 8) {
        out[(size_t)B_TOT * SEQ * HID + b * HID + row] = hlast;               // hx
        out[(size_t)B_TOT * SEQ * HID + B_TOT * HID + b * HID + row] = cx;    // cx
    }
}

extern "C" void kernel_launch(void* const* d_in, const int* in_sizes, int n_in,
                              void* d_out, int out_size, void* d_ws, size_t ws_size,
                              hipStream_t stream) {
    qlstm_kernel<<<512, 64, 0, stream>>>(
        (const float*)d_in[0],
        (const float*)d_in[1],  (const float*)d_in[2],  (const float*)d_in[3],
        (const float*)d_in[4],  (const float*)d_in[5],  (const float*)d_in[6],
        (const float*)d_in[7],  (const float*)d_in[8],  (const float*)d_in[9],
        (const float*)d_in[10], (const float*)d_in[11], (const float*)d_in[12],
        (float*)d_out);
}

// Round 2
// 30.043 us; speedup vs baseline: 1.0006x; 1.0006x over previous
//
#include <hip/hip_runtime.h>

#define B_TOT 1024
#define SEQ 64
#define IND 32
#define HID 8
#define BPB 4   // batches per block

// DPP helper (VALU-rate cross-lane)
template<int CTRL>
__device__ __forceinline__ float dppf(float v) {
    return __int_as_float(__builtin_amdgcn_update_dpp(
        0, __float_as_int(v), CTRL, 0xF, 0xF, true));
}

__global__ __launch_bounds__(512, 1) void qlstm_kernel(
    const float* __restrict__ xin,
    const float* __restrict__ Wf, const float* __restrict__ bf, const float* __restrict__ thf,
    const float* __restrict__ Wi, const float* __restrict__ bi, const float* __restrict__ thi,
    const float* __restrict__ Wu, const float* __restrict__ bu, const float* __restrict__ thu,
    const float* __restrict__ Wo, const float* __restrict__ bo, const float* __restrict__ tho,
    float* __restrict__ out)
{
    // z[b][t][gr]: x-projection + bias + theta, padded for bank-conflict-free access
    __shared__ float zs[BPB][SEQ + 1][33];

    const int tid = threadIdx.x;

    // ---------------- pass 1: z = W.x + b + theta (fully parallel) ----------------
    {
        const int sub = tid >> 8;        // 0: gr 0-15, 1: gr 16-31 (wave-uniform)
        const int idx = tid & 255;
        const int bl  = idx >> 6;        // batch within block
        const int t   = idx & 63;
        const int gb  = blockIdx.x * BPB + bl;
        const float4* xp = (const float4*)(xin + ((size_t)gb * SEQ + t) * IND);
        float4 x4[8];
        #pragma unroll
        for (int k = 0; k < 8; ++k) x4[k] = xp[k];

        #pragma unroll
        for (int j = 0; j < 16; ++j) {
            const int row = j & 7;
            // gate = sub*2 + (j>>3); uniform ternaries -> s_cselect on pointers
            const float* W = sub ? (j < 8 ? Wu : Wo) : (j < 8 ? Wf : Wi);
            const float* B = sub ? (j < 8 ? bu : bo) : (j < 8 ? bf : bi);
            const float* T = sub ? (j < 8 ? thu : tho) : (j < 8 ? thf : thi);
            const float4* wr = (const float4*)(W + row * 40);
            float a0 = B[row] + T[row], a1 = 0.f, a2 = 0.f, a3 = 0.f;
            #pragma unroll
            for (int k = 0; k < 8; ++k) {
                float4 w4 = wr[k];
                a0 = fmaf(w4.x, x4[k].x, a0);
                a1 = fmaf(w4.y, x4[k].y, a1);
                a2 = fmaf(w4.z, x4[k].z, a2);
                a3 = fmaf(w4.w, x4[k].w, a3);
            }
            zs[bl][t][(sub << 4) | j] = (a0 + a1) + (a2 + a3);
        }
    }

    __syncthreads();
    if (tid >= 64) return;   // pass 2 runs on wave 0 only

    // ---------------- pass 2: serial recurrence, all cross-lane via DPP ----------------
    const int lane = tid;
    const int b    = lane >> 4;      // batch within block (16 lanes per batch)
    const int l16  = lane & 15;
    const int p    = l16 >> 3;       // channel-pair selector: lane owns gates {p, p+2}
    const int r    = l16 & 7;        // row / wire
    const int gb   = blockIdx.x * BPB + b;
    const bool isP0 = (p == 0);

    // h-dot weights, pre-permuted to the DPP all-gather order hv[k] = h[r ^ m[k]]
    const int m[8] = {0, 1, 2, 3, 7, 6, 5, 4};
    const float* WA = p ? Wi : Wf;   // channel A: gate p   (0=f, 1=i)
    const float* WB = p ? Wo : Wu;   // channel B: gate p+2 (2=update, 3=o)
    float whA[8], whB[8];
    #pragma unroll
    for (int k = 0; k < 8; ++k) {
        whA[k] = WA[r * 40 + 32 + (r ^ m[k])];
        whB[k] = WB[r * 40 + 32 + (r ^ m[k])];
    }
    // channel A is always sigmoid; channel B: tanh (gate 2) if p==0 else sigmoid (gate 3)
    const float esB = p ? -1.0f : 2.0f;
    const float cAB = p ? 0.0f : 1.0f;
    const float cBB = p ? 1.0f : -2.0f;

    float* obase = out + (size_t)gb * (SEQ * HID);

    float cx = 0.f, hlast = 0.f;
    float hv[8] = {0.f, 0.f, 0.f, 0.f, 0.f, 0.f, 0.f, 0.f};
    float zA = zs[b][0][p * 8 + r];
    float zB = zs[b][0][p * 8 + r + 16];

    #pragma unroll 2
    for (int t = 0; t < SEQ; ++t) {
        // prefetch next step's z (LDS latency hidden under this step's chain)
        const int tn = (t + 1) & 63;
        float zAn = zs[b][tn][p * 8 + r];
        float zBn = zs[b][tn][p * 8 + r + 16];

        // y = z + wh.h
        float yA = zA, yB = zB;
        #pragma unroll
        for (int k = 0; k < 8; ++k) {
            yA = fmaf(whA[k], hv[k], yA);
            yB = fmaf(whB[k], hv[k], yB);
        }

        // per-wire PauliZ expectation: cos(y)
        float cA = __builtin_amdgcn_cosf(__builtin_amdgcn_fractf(yA * 0.15915494309189535f));
        float cB = __builtin_amdgcn_cosf(__builtin_amdgcn_fractf(yB * 0.15915494309189535f));

        // prefix products over rows (wires): out[w>=1] = c0..cw, out[0] = c1..c7
        float vA = cA, wA = (r == 0) ? 1.0f : cA;
        float vB = cB, wB = (r == 0) ? 1.0f : cB;
        float tA, uA, tB, uB;
        tA = dppf<0x111>(vA); uA = dppf<0x111>(wA);
        tB = dppf<0x111>(vB); uB = dppf<0x111>(wB);
        vA *= (r >= 1) ? tA : 1.0f;  wA *= (r >= 1) ? uA : 1.0f;
        vB *= (r >= 1) ? tB : 1.0f;  wB *= (r >= 1) ? uB : 1.0f;
        tA = dppf<0x112>(vA); uA = dppf<0x112>(wA);
        tB = dppf<0x112>(vB); uB = dppf<0x112>(wB);
        vA *= (r >= 2) ? tA : 1.0f;  wA *= (r >= 2) ? uA : 1.0f;
        vB *= (r >= 2) ? tB : 1.0f;  wB *= (r >= 2) ? uB : 1.0f;
        tA = dppf<0x114>(vA); uA = dppf<0x114>(wA);
        tB = dppf<0x114>(vB); uB = dppf<0x114>(wB);
        vA *= (r >= 4) ? tA : 1.0f;  wA *= (r >= 4) ? uA : 1.0f;
        vB *= (r >= 4) ? tB : 1.0f;  wB *= (r >= 4) ? uB : 1.0f;
        float fmA = dppf<0x141>(wA);              // row_half_mirror: r0 <- w[7]
        float fmB = dppf<0x141>(wB);
        float qA = (r == 0) ? fmA : vA;
        float qB = (r == 0) ? fmB : vB;

        // activations
        float actA = __builtin_amdgcn_rcpf(1.0f + __expf(-qA));          // sigmoid
        float actB = fmaf(cBB, __builtin_amdgcn_rcpf(1.0f + __expf(qB * esB)), cAB);

        // gate exchange: ^8 = row_ror:8 (VALU)
        float oA = dppf<0x128>(actA);
        float oB = dppf<0x128>(actB);
        float fv = isP0 ? actA : oA;   // forget (gate 0)
        float iv = isP0 ? oA : actA;   // input  (gate 1)
        float gv = isP0 ? actB : oB;   // update (gate 2)
        float ov = isP0 ? oB : actB;   // output (gate 3)

        // LSTM cell (every lane carries its row's state; copies are consistent)
        cx = fmaf(fv, cx, iv * gv);
        float e2 = __expf(2.0f * cx);
        float th = 1.0f - 2.0f * __builtin_amdgcn_rcpf(1.0f + e2);
        float h  = ov * th;
        hlast = h;

        if (isP0) obase[t * HID + r] = h;

        // h all-gather across the 8-lane row group: hv[k] = h[r ^ m[k]]
        hv[0] = h;
        hv[1] = dppf<0xB1>(h);        // quad_perm ^1
        hv[2] = dppf<0x4E>(hv[0]);    // quad_perm ^2
        hv[3] = dppf<0x4E>(hv[1]);
        hv[4] = dppf<0x141>(hv[0]);   // half_mirror ^7
        hv[5] = dppf<0x141>(hv[1]);
        hv[6] = dppf<0x141>(hv[2]);
        hv[7] = dppf<0x141>(hv[3]);

        zA = zAn; zB = zBn;
    }

    if (isP0) {
        const size_t hx_off = (size_t)B_TOT * SEQ * HID;
        out[hx_off + (size_t)gb * HID + r] = hlast;
        out[hx_off + (size_t)B_TOT * HID + (size_t)gb * HID + r] = cx;
    }
}

extern "C" void kernel_launch(void* const* d_in, const int* in_sizes, int n_in,
                              void* d_out, int out_size, void* d_ws, size_t ws_size,
                              hipStream_t stream) {
    qlstm_kernel<<<256, 512, 0, stream>>>(
        (const float*)d_in[0],
        (const float*)d_in[1],  (const float*)d_in[2],  (const float*)d_in[3],
        (const float*)d_in[4],  (const float*)d_in[5],  (const float*)d_in[6],
        (const float*)d_in[7],  (const float*)d_in[8],  (const float*)d_in[9],
        (const float*)d_in[10], (const float*)d_in[11], (const float*)d_in[12],
        (float*)d_out);
}

// Round 3
// 29.311 us; speedup vs baseline: 1.0256x; 1.0250x over previous
//
#include <hip/hip_runtime.h>

#define B_TOT 1024
#define SEQ 64
#define IND 32
#define HID 8
#define BPB 4   // batches per block

typedef __attribute__((ext_vector_type(2))) float f2;

// DPP helper (VALU-rate cross-lane)
template<int CTRL>
__device__ __forceinline__ float dppf(float v) {
    return __int_as_float(__builtin_amdgcn_update_dpp(
        0, __float_as_int(v), CTRL, 0xF, 0xF, true));
}
template<int CTRL>
__device__ __forceinline__ f2 dpp2(f2 v) {
    f2 r;
    r.x = dppf<CTRL>(v.x);
    r.y = dppf<CTRL>(v.y);
    return r;
}

__global__ __launch_bounds__(512, 1) void qlstm_kernel(
    const float* __restrict__ xin,
    const float* __restrict__ Wf, const float* __restrict__ bf, const float* __restrict__ thf,
    const float* __restrict__ Wi, const float* __restrict__ bi, const float* __restrict__ thi,
    const float* __restrict__ Wu, const float* __restrict__ bu, const float* __restrict__ thu,
    const float* __restrict__ Wo, const float* __restrict__ bo, const float* __restrict__ tho,
    float* __restrict__ out)
{
    // z[b][t][gr]: x-projection + bias + theta, padded for bank-conflict-free access
    __shared__ float zs[BPB][SEQ + 1][33];

    const int tid = threadIdx.x;

    // ---------------- pass 1: z = W.x + b + theta (fully parallel) ----------------
    {
        const int sub = tid >> 8;        // 0: gr 0-15, 1: gr 16-31 (wave-uniform)
        const int idx = tid & 255;
        const int bl  = idx >> 6;        // batch within block
        const int t   = idx & 63;
        const int gb  = blockIdx.x * BPB + bl;
        const float4* xp = (const float4*)(xin + ((size_t)gb * SEQ + t) * IND);
        float4 x4[8];
        #pragma unroll
        for (int k = 0; k < 8; ++k) x4[k] = xp[k];

        #pragma unroll
        for (int j = 0; j < 16; ++j) {
            const int row = j & 7;
            const float* W = sub ? (j < 8 ? Wu : Wo) : (j < 8 ? Wf : Wi);
            const float* B = sub ? (j < 8 ? bu : bo) : (j < 8 ? bf : bi);
            const float* T = sub ? (j < 8 ? thu : tho) : (j < 8 ? thf : thi);
            const float4* wr = (const float4*)(W + row * 40);
            float a0 = B[row] + T[row], a1 = 0.f, a2 = 0.f, a3 = 0.f;
            #pragma unroll
            for (int k = 0; k < 8; ++k) {
                float4 w4 = wr[k];
                a0 = fmaf(w4.x, x4[k].x, a0);
                a1 = fmaf(w4.y, x4[k].y, a1);
                a2 = fmaf(w4.z, x4[k].z, a2);
                a3 = fmaf(w4.w, x4[k].w, a3);
            }
            zs[bl][t][(sub << 4) | j] = (a0 + a1) + (a2 + a3);
        }
    }

    __syncthreads();
    if (tid >= 64) return;   // pass 2 runs on wave 0 only

    // ---------------- pass 2: serial recurrence, packed f32, all cross-lane DPP ----------------
    const int lane = tid;
    const int b    = lane >> 4;      // batch within block
    const int l16  = lane & 15;
    const int p    = l16 >> 3;       // lane owns gate pair {p, p+2}
    const int r    = l16 & 7;        // row / wire
    const int gb   = blockIdx.x * BPB + b;
    const bool isP0 = (p == 0);
    const bool r0   = (r == 0);
    const bool ge1 = (r >= 1), ge2 = (r >= 2), ge4 = (r >= 4);

    // h-dot weights, pre-permuted to DPP all-gather order hv[k] = h[r ^ m[k]]
    const int m[8] = {0, 1, 2, 3, 7, 6, 5, 4};
    const float* WA = p ? Wi : Wf;   // channel A: gate p (sigmoid)
    const float* WB = p ? Wo : Wu;   // channel B: gate p+2 (p0: tanh, p1: sigmoid)
    f2 wh[8];
    #pragma unroll
    for (int k = 0; k < 8; ++k) {
        wh[k].x = WA[r * 40 + 32 + (r ^ m[k])];
        wh[k].y = WB[r * 40 + 32 + (r ^ m[k])];
    }
    const f2 esAB = {-1.0f, p ? -1.0f : 2.0f};   // exp argument scale
    const f2 cMul = { 1.0f, p ?  1.0f : -2.0f};  // act = cMul*rcp + cAdd
    const f2 cAdd = { 0.0f, p ?  0.0f :  1.0f};
    const f2 one2 = { 1.0f, 1.0f};

    float* obase = out + (size_t)gb * (SEQ * HID);

    float cx = 0.f, hlast = 0.f;
    float hv[8] = {0.f, 0.f, 0.f, 0.f, 0.f, 0.f, 0.f, 0.f};
    f2 z = { zs[b][0][l16], zs[b][0][l16 + 16] };

    #pragma unroll 2
    for (int t = 0; t < SEQ; ++t) {
        // prefetch next step's z (LDS latency hidden under this step's chain)
        const int tn = (t + 1) & 63;
        f2 zn = { zs[b][tn][l16], zs[b][tn][l16 + 16] };

        // y = z + wh.h   (packed, 2 accumulators)
        f2 y0 = z, y1 = {0.f, 0.f};
        #pragma unroll
        for (int k = 0; k < 4; ++k) {
            y0 += wh[2 * k]     * (f2){hv[2 * k],     hv[2 * k]};
            y1 += wh[2 * k + 1] * (f2){hv[2 * k + 1], hv[2 * k + 1]};
        }
        f2 y = y0 + y1;

        // per-wire PauliZ expectation: cos(y)
        f2 a = y * 0.15915494309189535f;
        a.x = __builtin_amdgcn_fractf(a.x);
        a.y = __builtin_amdgcn_fractf(a.y);
        f2 c;
        c.x = __builtin_amdgcn_cosf(a.x);
        c.y = __builtin_amdgcn_cosf(a.y);

        // wire-0 value: all-reduce product of (r==0 ? 1 : c) over the 8-lane group
        f2 mm = { r0 ? 1.0f : c.x, r0 ? 1.0f : c.y };
        mm *= dpp2<0xB1>(mm);    // quad_perm ^1
        mm *= dpp2<0x4E>(mm);    // quad_perm ^2
        mm *= dpp2<0x141>(mm);   // half_mirror (cross-quad within 8)

        // wires 1..7: inclusive prefix product (row_shr scan)
        f2 v = c, tt;
        tt = dpp2<0x111>(v); v *= ge1 ? tt : one2;
        tt = dpp2<0x112>(v); v *= ge2 ? tt : one2;
        tt = dpp2<0x114>(v); v *= ge4 ? tt : one2;

        f2 q = { r0 ? mm.x : v.x, r0 ? mm.y : v.y };

        // activations: e = exp(q*esAB); act = cMul/(1+e) + cAdd
        f2 arg = q * esAB;
        f2 e;
        e.x = __expf(arg.x);
        e.y = __expf(arg.y);
        f2 s = e + one2;
        f2 rr;
        rr.x = __builtin_amdgcn_rcpf(s.x);
        rr.y = __builtin_amdgcn_rcpf(s.y);
        f2 act = rr * cMul + cAdd;

        // gate exchange: row_ror:8 swaps p-halves
        float oA = dppf<0x128>(act.x);
        float oB = dppf<0x128>(act.y);
        float fv = isP0 ? act.x : oA;   // forget
        float iv = isP0 ? oA : act.x;   // input
        float gv = isP0 ? act.y : oB;   // update
        float ov = isP0 ? oB : act.y;   // output

        // LSTM cell
        cx = fmaf(fv, cx, iv * gv);
        float e2 = __expf(2.0f * cx);
        float th = fmaf(-2.0f, __builtin_amdgcn_rcpf(1.0f + e2), 1.0f);
        float h  = ov * th;
        hlast = h;

        if (isP0) obase[t * HID + r] = h;

        // h all-gather: hv[k] = h[r ^ m[k]]
        hv[0] = h;
        hv[1] = dppf<0xB1>(h);
        hv[2] = dppf<0x4E>(hv[0]);
        hv[3] = dppf<0x4E>(hv[1]);
        hv[4] = dppf<0x141>(hv[0]);
        hv[5] = dppf<0x141>(hv[1]);
        hv[6] = dppf<0x141>(hv[2]);
        hv[7] = dppf<0x141>(hv[3]);

        z = zn;
    }

    if (isP0) {
        const size_t hx_off = (size_t)B_TOT * SEQ * HID;
        out[hx_off + (size_t)gb * HID + r] = hlast;
        out[hx_off + (size_t)B_TOT * HID + (size_t)gb * HID + r] = cx;
    }
}

extern "C" void kernel_launch(void* const* d_in, const int* in_sizes, int n_in,
                              void* d_out, int out_size, void* d_ws, size_t ws_size,
                              hipStream_t stream) {
    qlstm_kernel<<<256, 512, 0, stream>>>(
        (const float*)d_in[0],
        (const float*)d_in[1],  (const float*)d_in[2],  (const float*)d_in[3],
        (const float*)d_in[4],  (const float*)d_in[5],  (const float*)d_in[6],
        (const float*)d_in[7],  (const float*)d_in[8],  (const float*)d_in[9],
        (const float*)d_in[10], (const float*)d_in[11], (const float*)d_in[12],
        (float*)d_out);
}